// Round 1
// baseline (605.384 us; speedup 1.0000x reference)
//
#include <hip/hip_runtime.h>
#include <hip/hip_bf16.h>

typedef short short8 __attribute__((ext_vector_type(8)));
typedef float f32x4 __attribute__((ext_vector_type(4)));
typedef unsigned short u16;
typedef unsigned short u16x4 __attribute__((ext_vector_type(4)));

#define BDIM 4
#define SEQ 2048
#define DMODEL 1024
#define NHEAD 16
#define DKH 64
#define MTOK 8192

__device__ __forceinline__ u16 f2bf(float f) {
  __hip_bfloat16 h = __float2bfloat16(f);
  return __builtin_bit_cast(u16, h);
}
__device__ __forceinline__ float bf2f(u16 u) {
  return __bfloat162float(__builtin_bit_cast(__hip_bfloat16, u));
}
__device__ __forceinline__ void gload_lds16(const void* g, void* l) {
  __builtin_amdgcn_global_load_lds(
      (const __attribute__((address_space(1))) void*)g,
      (__attribute__((address_space(3))) void*)l, 16, 0, 0);
}

// ---------------- lens from padding mask (auto-detect bool vs int32 layout) ----
__global__ void compute_lens(const unsigned char* __restrict__ mask, int* __restrict__ lens) {
  __shared__ int flag;
  __shared__ int cnt[4];
  const int tid = threadIdx.x;
  if (tid == 0) flag = 0;
  if (tid < 4) cnt[tid] = 0;
  __syncthreads();
  int found = 0;
  for (int i = tid; i < 8192; i += 256)
    if (mask[i] == 1 && (i & 3) != 0) found = 1;   // bool layout has 1-bytes off 4-alignment
  if (found) atomicOr(&flag, 1);
  __syncthreads();
  int l0 = 0, l1 = 0, l2 = 0, l3 = 0;
  if (flag) {
    for (int i = tid; i < 8192; i += 256) {
      int z = (mask[i] == 0);
      int b = i >> 11;
      l0 += z & (b == 0); l1 += z & (b == 1); l2 += z & (b == 2); l3 += z & (b == 3);
    }
  } else {
    const int* mi = (const int*)mask;
    for (int i = tid; i < 8192; i += 256) {
      int z = (mi[i] == 0);
      int b = i >> 11;
      l0 += z & (b == 0); l1 += z & (b == 1); l2 += z & (b == 2); l3 += z & (b == 3);
    }
  }
  if (l0) atomicAdd(&cnt[0], l0);
  if (l1) atomicAdd(&cnt[1], l1);
  if (l2) atomicAdd(&cnt[2], l2);
  if (l3) atomicAdd(&cnt[3], l3);
  __syncthreads();
  if (tid < 4) lens[tid] = cnt[tid];
}

// ---------------- weight convert f32[K][N] -> bf16[N][K] (transpose) ----------
__global__ void convT(const float* __restrict__ in, u16* __restrict__ out,
                      int K, int N, long inz, long outz) {
  __shared__ float t[32][33];
  const int n0 = blockIdx.x * 32, k0 = blockIdx.y * 32;
  const float* ip = in + (size_t)blockIdx.z * inz;
  u16* op = out + (size_t)blockIdx.z * outz;
  const int tx = threadIdx.x & 31, ty = threadIdx.x >> 5;
  for (int i = ty; i < 32; i += 8)
    t[i][tx] = ip[(size_t)(k0 + i) * N + n0 + tx];
  __syncthreads();
  for (int i = ty; i < 32; i += 8)
    op[(size_t)(n0 + i) * K + k0 + tx] = f2bf(t[tx][i]);
}

// ---------------- RMSNorm: f32 [row][1024] -> bf16 --------------------------
__global__ void rmsnorm_kernel(const float* __restrict__ in, const float* __restrict__ g,
                               u16* __restrict__ out) {
  __shared__ float psum[4];
  const int row = blockIdx.x, tid = threadIdx.x;
  const float4 x = ((const float4*)(in + (size_t)row * 1024))[tid];
  float ss = x.x * x.x + x.y * x.y + x.z * x.z + x.w * x.w;
  for (int m = 1; m < 64; m <<= 1) ss += __shfl_xor(ss, m, 64);
  if ((tid & 63) == 0) psum[tid >> 6] = ss;
  __syncthreads();
  const float tot = psum[0] + psum[1] + psum[2] + psum[3];
  const float inv = rsqrtf(tot * (1.0f / 1024.0f));
  const float4 gv = ((const float4*)g)[tid];
  u16x4 o;
  o[0] = f2bf(gv.x * x.x * inv); o[1] = f2bf(gv.y * x.y * inv);
  o[2] = f2bf(gv.z * x.z * inv); o[3] = f2bf(gv.w * x.w * inv);
  *(u16x4*)&out[(size_t)row * 1024 + tid * 4] = o;
}

// ---------------- bf16 GEMM: C[M,N] = A[M,K] @ Bt[N,K]^T, fused epilogues ----
// 128x128 tile, BK=64, 4 waves (2x2 of 64x64), LDS row stride 72 elems (144B).
#define LDST 72
enum { MQKV = 0, MSA = 1, MB16 = 2, MSILU = 3, MFF2 = 4 };

template <int MODE>
__global__ void gemm_bf16(const u16* __restrict__ A, const u16* __restrict__ Bt,
                          const int K, const int N,
                          u16* __restrict__ oq, u16* __restrict__ ok, u16* __restrict__ ov,
                          float* __restrict__ of, const float* __restrict__ afp,
                          u16* __restrict__ ob) {
  __shared__ u16 ldsA[1152 * 8];
  __shared__ u16 ldsB[1152 * 8];
  const int tid = threadIdx.x;
  const int l = tid & 63, wid = tid >> 6;
  const int wr = wid >> 1, wc = wid & 1;
  const int lane16 = l & 15, lgrp = l >> 4;
  const int row0 = blockIdx.y * 128, col0 = blockIdx.x * 128;
  const u16* Abase = A + (size_t)row0 * K;
  const u16* Bbase = Bt + (size_t)col0 * K;

  f32x4 zero = {0.f, 0.f, 0.f, 0.f};
  f32x4 acc[4][4];
#pragma unroll
  for (int i = 0; i < 4; i++)
#pragma unroll
    for (int j = 0; j < 4; j++) acc[i][j] = zero;

  const int nkt = K >> 6;
  for (int kt = 0; kt < nkt; ++kt) {
    const int k0 = kt * 64;
    // stage A,B tiles: 1152 16B-chunks each (9 chunks/row: 8 data + 1 pad)
#pragma unroll
    for (int it = 0; it < 5; ++it) {
      const int blk = wid + it * 4;
      if (blk < 18) {
        const unsigned chunk = blk * 64 + l;
        const unsigned r = chunk / 9u;
        const unsigned cw = chunk - r * 9u;
        const unsigned koff = (cw == 8u) ? 0u : cw * 8u;
        gload_lds16(Abase + (size_t)r * K + k0 + koff, &ldsA[blk * 512]);
        gload_lds16(Bbase + (size_t)r * K + k0 + koff, &ldsB[blk * 512]);
      }
    }
    __syncthreads();
#pragma unroll
    for (int ks = 0; ks < 2; ++ks) {
      short8 a[4], b[4];
#pragma unroll
      for (int i = 0; i < 4; ++i)
        a[i] = *(const short8*)&ldsA[(wr * 64 + i * 16 + lane16) * LDST + ks * 32 + lgrp * 8];
#pragma unroll
      for (int i = 0; i < 4; ++i)
        b[i] = *(const short8*)&ldsB[(wc * 64 + i * 16 + lane16) * LDST + ks * 32 + lgrp * 8];
#pragma unroll
      for (int mi = 0; mi < 4; ++mi)
#pragma unroll
        for (int ni = 0; ni < 4; ++ni)
          acc[mi][ni] = __builtin_amdgcn_mfma_f32_16x16x32_bf16(a[mi], b[ni], acc[mi][ni], 0, 0, 0);
    }
    __syncthreads();
  }

  // epilogue: C row s = row0+wr*64+mi*16+lgrp*4+reg ; col j = col0+wc*64+ni*16+lane16
#pragma unroll
  for (int mi = 0; mi < 4; ++mi) {
    const int sbase = row0 + wr * 64 + mi * 16 + lgrp * 4;
#pragma unroll
    for (int ni = 0; ni < 4; ++ni) {
      const int j = col0 + wc * 64 + ni * 16 + lane16;
      if (MODE == MQKV) {
        const int which = j >> 10, rr = j & 1023, h = rr >> 6, kk = rr & 63;
        const int bb = sbase >> 11, sr = sbase & 2047;
        const int bh = bb * 16 + h;
        if (which == 2) {
          u16x4 pk;
#pragma unroll
          for (int r = 0; r < 4; ++r) pk[r] = f2bf(acc[mi][ni][r]);
          *(u16x4*)&ov[((size_t)bh * 64 + kk) * 2048 + sr] = pk;  // V stored transposed [bh][dk][t]
        } else {
          u16* dst = (which == 0) ? oq : ok;
#pragma unroll
          for (int r = 0; r < 4; ++r)
            dst[((size_t)bh * 2048 + sr + r) * 64 + kk] = f2bf(acc[mi][ni][r]);
        }
      } else if (MODE == MSA) {
#pragma unroll
        for (int r = 0; r < 4; ++r) {
          const size_t idx = (size_t)(sbase + r) * 1024 + j;
          of[idx] = afp[idx] + acc[mi][ni][r];
        }
      } else if (MODE == MB16) {
#pragma unroll
        for (int r = 0; r < 4; ++r)
          ob[(size_t)(sbase + r) * N + j] = f2bf(acc[mi][ni][r]);
      } else if (MODE == MSILU) {
#pragma unroll
        for (int r = 0; r < 4; ++r) {
          const size_t idx = (size_t)(sbase + r) * N + j;
          const float c1 = bf2f(ob[idx]);
          const float s = c1 / (1.0f + __expf(-c1));
          ob[idx] = f2bf(s * acc[mi][ni][r]);
        }
      } else {  // MFF2
#pragma unroll
        for (int r = 0; r < 4; ++r) {
          const size_t idx = (size_t)(sbase + r) * 1024 + j;
          of[idx] = of[idx] + acc[mi][ni][r];
        }
      }
    }
  }
}

// ---------------- flash attention: per (b,h), 64 Q rows per block ------------
__global__ void attn_kernel(const u16* __restrict__ qb, const u16* __restrict__ kb,
                            const u16* __restrict__ vT, u16* __restrict__ obuf,
                            const int* __restrict__ lens) {
  __shared__ u16 Kl[64 * 72];
  __shared__ u16 Vl[64 * 72];   // [dk][t] tile
  __shared__ u16 Pl[4][16 * 72];
  const int tid = threadIdx.x;
  const int l = tid & 63, wid = tid >> 6;
  const int lane16 = l & 15, lgrp = l >> 4;
  const int bh = blockIdx.x, b = bh >> 4, h = bh & 15;
  const int q0 = blockIdx.y * 64;
  const int len = lens[b];

  if (q0 >= len) {  // fully padded query tile -> zero output rows
    const int r = tid >> 2, c = (tid & 3) * 16;
    short8 z = {0, 0, 0, 0, 0, 0, 0, 0};
    const size_t base = ((size_t)(b * 2048 + q0 + r)) * 1024 + h * 64 + c;
    *(short8*)&obuf[base] = z;
    *(short8*)&obuf[base + 8] = z;
    return;
  }

  const int qrow = q0 + wid * 16 + lane16;
  const u16* qp = qb + ((size_t)bh * 2048 + qrow) * 64;
  const short8 qf0 = *(const short8*)(qp + lgrp * 8);
  const short8 qf1 = *(const short8*)(qp + 32 + lgrp * 8);

  float m_run[4], l_run[4];
  f32x4 zero = {0.f, 0.f, 0.f, 0.f};
  f32x4 o_acc[4];
#pragma unroll
  for (int r = 0; r < 4; ++r) { m_run[r] = -1e30f; l_run[r] = 0.f; }
#pragma unroll
  for (int i = 0; i < 4; ++i) o_acc[i] = zero;

  const int nt = (len + 63) >> 6;
  for (int kt = 0; kt < nt; ++kt) {
    const int t0 = kt * 64;
    __syncthreads();
    {
      const int r = tid >> 2, c = (tid & 3) * 16;
      const u16* ksrc = kb + ((size_t)bh * 2048 + t0 + r) * 64 + c;
      *(short8*)&Kl[r * 72 + c] = *(const short8*)ksrc;
      *(short8*)&Kl[r * 72 + c + 8] = *(const short8*)(ksrc + 8);
      const u16* vsrc = vT + ((size_t)bh * 64 + r) * 2048 + t0 + c;
      *(short8*)&Vl[r * 72 + c] = *(const short8*)vsrc;
      *(short8*)&Vl[r * 72 + c + 8] = *(const short8*)(vsrc + 8);
    }
    __syncthreads();

    f32x4 sc[4];
#pragma unroll
    for (int i = 0; i < 4; ++i) sc[i] = zero;
#pragma unroll
    for (int ks2 = 0; ks2 < 2; ++ks2) {
      const short8 qf = ks2 ? qf1 : qf0;
#pragma unroll
      for (int ni = 0; ni < 4; ++ni) {
        const short8 kf = *(const short8*)&Kl[(ni * 16 + lane16) * 72 + ks2 * 32 + lgrp * 8];
        sc[ni] = __builtin_amdgcn_mfma_f32_16x16x32_bf16(qf, kf, sc[ni], 0, 0, 0);
      }
    }

    const bool full = (t0 + 64) <= len;
#pragma unroll
    for (int r = 0; r < 4; ++r) {
      float v0 = sc[0][r] * 0.125f, v1 = sc[1][r] * 0.125f;
      float v2 = sc[2][r] * 0.125f, v3 = sc[3][r] * 0.125f;
      if (!full) {
        if (t0 + 0 + lane16 >= len) v0 = -1e30f;
        if (t0 + 16 + lane16 >= len) v1 = -1e30f;
        if (t0 + 32 + lane16 >= len) v2 = -1e30f;
        if (t0 + 48 + lane16 >= len) v3 = -1e30f;
      }
      float mx = fmaxf(fmaxf(v0, v1), fmaxf(v2, v3));
      for (int m = 1; m < 16; m <<= 1) mx = fmaxf(mx, __shfl_xor(mx, m, 64));
      const float mnew = fmaxf(m_run[r], mx);
      const float fac = __expf(m_run[r] - mnew);
      const float p0 = __expf(v0 - mnew), p1 = __expf(v1 - mnew);
      const float p2 = __expf(v2 - mnew), p3 = __expf(v3 - mnew);
      float sum = p0 + p1 + p2 + p3;
      for (int m = 1; m < 16; m <<= 1) sum += __shfl_xor(sum, m, 64);
      l_run[r] = l_run[r] * fac + sum;
      m_run[r] = mnew;
#pragma unroll
      for (int di = 0; di < 4; ++di) o_acc[di][r] *= fac;
      const int prow = lgrp * 4 + r;
      Pl[wid][prow * 72 + 0 + lane16] = f2bf(p0);
      Pl[wid][prow * 72 + 16 + lane16] = f2bf(p1);
      Pl[wid][prow * 72 + 32 + lane16] = f2bf(p2);
      Pl[wid][prow * 72 + 48 + lane16] = f2bf(p3);
    }

#pragma unroll
    for (int ks2 = 0; ks2 < 2; ++ks2) {
      const short8 pf = *(const short8*)&Pl[wid][lane16 * 72 + ks2 * 32 + lgrp * 8];
#pragma unroll
      for (int di = 0; di < 4; ++di) {
        const short8 vf = *(const short8*)&Vl[(di * 16 + lane16) * 72 + ks2 * 32 + lgrp * 8];
        o_acc[di] = __builtin_amdgcn_mfma_f32_16x16x32_bf16(pf, vf, o_acc[di], 0, 0, 0);
      }
    }
  }

#pragma unroll
  for (int r = 0; r < 4; ++r) {
    const int qr = q0 + wid * 16 + lgrp * 4 + r;
    const float invl = 1.0f / l_run[r];
    const bool valid = (qr < len);
    const size_t base = ((size_t)(b * 2048 + qr)) * 1024 + h * 64;
#pragma unroll
    for (int di = 0; di < 4; ++di) {
      const float v = valid ? o_acc[di][r] * invl : 0.f;
      obuf[base + di * 16 + lane16] = f2bf(v);
    }
  }
}

// ---------------- launch ------------------------------------------------------
extern "C" void kernel_launch(void* const* d_in, const int* in_sizes, int n_in,
                              void* d_out, int out_size, void* d_ws, size_t ws_size,
                              hipStream_t stream) {
  const float* src = (const float*)d_in[0];
  const unsigned char* mask = (const unsigned char*)d_in[1];
  const float* Wq = (const float*)d_in[2];
  const float* Wk = (const float*)d_in[3];
  const float* Wv = (const float*)d_in[4];
  const float* Wo = (const float*)d_in[5];
  const float* g1 = (const float*)d_in[6];
  const float* g2 = (const float*)d_in[7];
  const float* W1 = (const float*)d_in[8];
  const float* V1 = (const float*)d_in[9];
  const float* W2 = (const float*)d_in[10];
  float* out = (float*)d_out;
  char* ws = (char*)d_ws;

  int* lens   = (int*)ws;
  u16* WqkvT  = (u16*)(ws + 256);        // [3072][1024]
  u16* WoT    = (u16*)(ws + 6291712);    // [1024][1024]
  u16* W1T    = (u16*)(ws + 8388864);    // [4096][1024]
  u16* V1T    = (u16*)(ws + 16777472);   // [4096][1024]
  u16* W2T    = (u16*)(ws + 25166080);   // [1024][4096]
  u16* xb     = (u16*)(ws + 33554688);   // [8192][1024] bf16 (x, later y)
  u16* qbf    = (u16*)(ws + 50331904);   // [64][2048][64]
  u16* kbf    = (u16*)(ws + 67109120);   // [64][2048][64]
  u16* vTb    = (u16*)(ws + 83886336);   // [64][64][2048]
  u16* obf    = (u16*)(ws + 100663552);  // [8192][1024]
  u16* c1     = qbf;                     // [8192][4096] reuses q|k|vT|o region (64 MiB)

  compute_lens<<<1, 256, 0, stream>>>(mask, lens);
  convT<<<dim3(2, 32, 16), 256, 0, stream>>>(Wq, WqkvT, 1024, 64, 65536, 65536);
  convT<<<dim3(2, 32, 16), 256, 0, stream>>>(Wk, WqkvT + 1024 * 1024, 1024, 64, 65536, 65536);
  convT<<<dim3(2, 32, 16), 256, 0, stream>>>(Wv, WqkvT + 2048 * 1024, 1024, 64, 65536, 65536);
  convT<<<dim3(32, 32, 1), 256, 0, stream>>>(Wo, WoT, 1024, 1024, 0, 0);
  convT<<<dim3(128, 32, 1), 256, 0, stream>>>(W1, W1T, 1024, 4096, 0, 0);
  convT<<<dim3(128, 32, 1), 256, 0, stream>>>(V1, V1T, 1024, 4096, 0, 0);
  convT<<<dim3(32, 128, 1), 256, 0, stream>>>(W2, W2T, 4096, 1024, 0, 0);

  rmsnorm_kernel<<<8192, 256, 0, stream>>>(src, g1, xb);
  gemm_bf16<MQKV><<<dim3(24, 64), 256, 0, stream>>>(xb, WqkvT, 1024, 3072,
                                                    qbf, kbf, vTb, nullptr, nullptr, nullptr);
  attn_kernel<<<dim3(64, 32), 256, 0, stream>>>(qbf, kbf, vTb, obf, lens);
  gemm_bf16<MSA><<<dim3(8, 64), 256, 0, stream>>>(obf, WoT, 1024, 1024,
                                                  nullptr, nullptr, nullptr, out, src, nullptr);
  rmsnorm_kernel<<<8192, 256, 0, stream>>>(out, g2, xb);
  gemm_bf16<MB16><<<dim3(32, 64), 256, 0, stream>>>(xb, W1T, 1024, 4096,
                                                    nullptr, nullptr, nullptr, nullptr, nullptr, c1);
  gemm_bf16<MSILU><<<dim3(32, 64), 256, 0, stream>>>(xb, V1T, 1024, 4096,
                                                     nullptr, nullptr, nullptr, nullptr, nullptr, c1);
  gemm_bf16<MFF2><<<dim3(8, 64), 256, 0, stream>>>(c1, W2T, 4096, 1024,
                                                   nullptr, nullptr, nullptr, out, nullptr, nullptr);
}

// Round 3
// 513.244 us; speedup vs baseline: 1.1795x; 1.1795x over previous
//
#include <hip/hip_runtime.h>
#include <hip/hip_bf16.h>

typedef short short8 __attribute__((ext_vector_type(8)));
typedef float f32x4 __attribute__((ext_vector_type(4)));
typedef float f32x16 __attribute__((ext_vector_type(16)));
typedef unsigned short u16;
typedef unsigned short u16x4 __attribute__((ext_vector_type(4)));

__device__ __forceinline__ u16 f2bf(float f) {
  __hip_bfloat16 h = __float2bfloat16(f);
  return __builtin_bit_cast(u16, h);
}
__device__ __forceinline__ float bf2f(u16 u) {
  return __bfloat162float(__builtin_bit_cast(__hip_bfloat16, u));
}
__device__ __forceinline__ void gload_lds16(const void* g, void* l) {
  __builtin_amdgcn_global_load_lds(
      (const __attribute__((address_space(1))) void*)g,
      (__attribute__((address_space(3))) void*)l, 16, 0, 0);
}
__device__ __forceinline__ unsigned cvtpk(float lo, float hi) {
  unsigned r;
  asm("v_cvt_pk_bf16_f32 %0, %1, %2" : "=v"(r) : "v"(lo), "v"(hi));
  return r;
}

// ---------------- lens from padding mask (auto-detect bool vs int32 layout) ----
__global__ void compute_lens(const unsigned char* __restrict__ mask, int* __restrict__ lens) {
  __shared__ int flag;
  __shared__ int cnt[4];
  const int tid = threadIdx.x;
  if (tid == 0) flag = 0;
  if (tid < 4) cnt[tid] = 0;
  __syncthreads();
  int found = 0;
  for (int i = tid; i < 8192; i += 256)
    if (mask[i] == 1 && (i & 3) != 0) found = 1;
  if (found) atomicOr(&flag, 1);
  __syncthreads();
  int l0 = 0, l1 = 0, l2 = 0, l3 = 0;
  if (flag) {
    for (int i = tid; i < 8192; i += 256) {
      int z = (mask[i] == 0);
      int b = i >> 11;
      l0 += z & (b == 0); l1 += z & (b == 1); l2 += z & (b == 2); l3 += z & (b == 3);
    }
  } else {
    const int* mi = (const int*)mask;
    for (int i = tid; i < 8192; i += 256) {
      int z = (mi[i] == 0);
      int b = i >> 11;
      l0 += z & (b == 0); l1 += z & (b == 1); l2 += z & (b == 2); l3 += z & (b == 3);
    }
  }
  if (l0) atomicAdd(&cnt[0], l0);
  if (l1) atomicAdd(&cnt[1], l1);
  if (l2) atomicAdd(&cnt[2], l2);
  if (l3) atomicAdd(&cnt[3], l3);
  __syncthreads();
  if (tid < 4) lens[tid] = cnt[tid];
}

// ---------------- weight convert f32[K][N] -> bf16[N][K] (transpose) ----------
__global__ void convT(const float* __restrict__ in, u16* __restrict__ out,
                      int K, int N, long inz, long outz) {
  __shared__ float t[32][33];
  const int n0 = blockIdx.x * 32, k0 = blockIdx.y * 32;
  const float* ip = in + (size_t)blockIdx.z * inz;
  u16* op = out + (size_t)blockIdx.z * outz;
  const int tx = threadIdx.x & 31, ty = threadIdx.x >> 5;
  for (int i = ty; i < 32; i += 8)
    t[i][tx] = ip[(size_t)(k0 + i) * N + n0 + tx];
  __syncthreads();
  for (int i = ty; i < 32; i += 8)
    op[(size_t)(n0 + i) * K + k0 + tx] = f2bf(t[tx][i]);
}

// ---------------- RMSNorm: f32 [row][1024] -> bf16 --------------------------
__global__ void rmsnorm_kernel(const float* __restrict__ in, const float* __restrict__ g,
                               u16* __restrict__ out) {
  __shared__ float psum[4];
  const int row = blockIdx.x, tid = threadIdx.x;
  const float4 x = ((const float4*)(in + (size_t)row * 1024))[tid];
  float ss = x.x * x.x + x.y * x.y + x.z * x.z + x.w * x.w;
  for (int m = 1; m < 64; m <<= 1) ss += __shfl_xor(ss, m, 64);
  if ((tid & 63) == 0) psum[tid >> 6] = ss;
  __syncthreads();
  const float tot = psum[0] + psum[1] + psum[2] + psum[3];
  const float inv = rsqrtf(tot * (1.0f / 1024.0f));
  const float4 gv = ((const float4*)g)[tid];
  u16x4 o;
  o[0] = f2bf(gv.x * x.x * inv); o[1] = f2bf(gv.y * x.y * inv);
  o[2] = f2bf(gv.z * x.z * inv); o[3] = f2bf(gv.w * x.w * inv);
  *(u16x4*)&out[(size_t)row * 1024 + tid * 4] = o;
}

// ---------------- bf16 GEMM: C[M,N] = A[M,K] @ Bt[N,K]^T, fused epilogues ----
#define LDST 72
enum { MQKV = 0, MSA = 1, MB16 = 2, MSILU = 3, MFF2 = 4 };

template <int MODE>
__global__ void gemm_bf16(const u16* __restrict__ A, const u16* __restrict__ Bt,
                          const int K, const int N,
                          u16* __restrict__ oq, u16* __restrict__ ok, u16* __restrict__ ov,
                          float* __restrict__ of, const float* __restrict__ afp,
                          u16* __restrict__ ob) {
  __shared__ u16 ldsA[1152 * 8];
  __shared__ u16 ldsB[1152 * 8];
  const int tid = threadIdx.x;
  const int l = tid & 63, wid = tid >> 6;
  const int wr = wid >> 1, wc = wid & 1;
  const int lane16 = l & 15, lgrp = l >> 4;
  const int row0 = blockIdx.y * 128, col0 = blockIdx.x * 128;
  const u16* Abase = A + (size_t)row0 * K;
  const u16* Bbase = Bt + (size_t)col0 * K;

  f32x4 zero = {0.f, 0.f, 0.f, 0.f};
  f32x4 acc[4][4];
#pragma unroll
  for (int i = 0; i < 4; i++)
#pragma unroll
    for (int j = 0; j < 4; j++) acc[i][j] = zero;

  const int nkt = K >> 6;
  for (int kt = 0; kt < nkt; ++kt) {
    const int k0 = kt * 64;
#pragma unroll
    for (int it = 0; it < 5; ++it) {
      const int blk = wid + it * 4;
      if (blk < 18) {
        const unsigned chunk = blk * 64 + l;
        const unsigned r = chunk / 9u;
        const unsigned cw = chunk - r * 9u;
        const unsigned koff = (cw == 8u) ? 0u : cw * 8u;
        gload_lds16(Abase + (size_t)r * K + k0 + koff, &ldsA[blk * 512]);
        gload_lds16(Bbase + (size_t)r * K + k0 + koff, &ldsB[blk * 512]);
      }
    }
    __syncthreads();
#pragma unroll
    for (int ks = 0; ks < 2; ++ks) {
      short8 a[4], b[4];
#pragma unroll
      for (int i = 0; i < 4; ++i)
        a[i] = *(const short8*)&ldsA[(wr * 64 + i * 16 + lane16) * LDST + ks * 32 + lgrp * 8];
#pragma unroll
      for (int i = 0; i < 4; ++i)
        b[i] = *(const short8*)&ldsB[(wc * 64 + i * 16 + lane16) * LDST + ks * 32 + lgrp * 8];
#pragma unroll
      for (int mi = 0; mi < 4; ++mi)
#pragma unroll
        for (int ni = 0; ni < 4; ++ni)
          acc[mi][ni] = __builtin_amdgcn_mfma_f32_16x16x32_bf16(a[mi], b[ni], acc[mi][ni], 0, 0, 0);
    }
    __syncthreads();
  }

#pragma unroll
  for (int mi = 0; mi < 4; ++mi) {
    const int sbase = row0 + wr * 64 + mi * 16 + lgrp * 4;
#pragma unroll
    for (int ni = 0; ni < 4; ++ni) {
      const int j = col0 + wc * 64 + ni * 16 + lane16;
      if (MODE == MQKV) {
        const int which = j >> 10, rr = j & 1023, h = rr >> 6, kk = rr & 63;
        const int bb = sbase >> 11, sr = sbase & 2047;
        const int bh = bb * 16 + h;
        if (which == 2) {
          u16x4 pk;
#pragma unroll
          for (int r = 0; r < 4; ++r) pk[r] = f2bf(acc[mi][ni][r]);
          *(u16x4*)&ov[((size_t)bh * 64 + kk) * 2048 + sr] = pk;  // V^T [bh][dk][t]
        } else {
          u16* dst = (which == 0) ? oq : ok;
          const float scl = (which == 0) ? 0.125f : 1.0f;  // fold softmax scale into Q
#pragma unroll
          for (int r = 0; r < 4; ++r)
            dst[((size_t)bh * 2048 + sr + r) * 64 + kk] = f2bf(acc[mi][ni][r] * scl);
        }
      } else if (MODE == MSA) {
#pragma unroll
        for (int r = 0; r < 4; ++r) {
          const size_t idx = (size_t)(sbase + r) * 1024 + j;
          of[idx] = afp[idx] + acc[mi][ni][r];
        }
      } else if (MODE == MB16) {
#pragma unroll
        for (int r = 0; r < 4; ++r)
          ob[(size_t)(sbase + r) * N + j] = f2bf(acc[mi][ni][r]);
      } else if (MODE == MSILU) {
#pragma unroll
        for (int r = 0; r < 4; ++r) {
          const size_t idx = (size_t)(sbase + r) * N + j;
          const float c1 = bf2f(ob[idx]);
          const float s = c1 / (1.0f + __expf(-c1));
          ob[idx] = f2bf(s * acc[mi][ni][r]);
        }
      } else {  // MFF2
#pragma unroll
        for (int r = 0; r < 4; ++r) {
          const size_t idx = (size_t)(sbase + r) * 1024 + j;
          of[idx] = of[idx] + acc[mi][ni][r];
        }
      }
    }
  }
}

// ---------------- attention v2: 4 warps x 32 Q-rows, swapped 32x32 MFMA ------
// P computed in-register (lane = query); K/V^T tiles [64][64] bf16 in LDS with
// XOR chunk swizzle (read row stride 128B would otherwise be 32-way conflict).
__global__ void attn2_kernel(const u16* __restrict__ qb, const u16* __restrict__ kb,
                             const u16* __restrict__ vT, u16* __restrict__ obuf,
                             const int* __restrict__ lens) {
  // K tile [0..4095], V^T tile [4096..8191]; epilogue reuses as 4 x [32][72]
  __shared__ u16 sm[9216];
  const int tid = threadIdx.x;
  const int l = tid & 63, wid = tid >> 6;
  const int l31 = l & 31, hi = l >> 5;
  const int bh = blockIdx.x, b = bh >> 4, h = bh & 15;
  const int q0 = blockIdx.y * 128;
  const int len = lens[b];

  if (q0 >= len) {  // fully padded query block -> zero 128 rows
    short8 z = {0, 0, 0, 0, 0, 0, 0, 0};
#pragma unroll
    for (int c = 0; c < 4; ++c) {
      const int ck = c * 256 + tid;
      const int r = ck >> 3, j = ck & 7;
      *(short8*)&obuf[((size_t)b * 2048 + q0 + r) * 1024 + h * 64 + j * 8] = z;
    }
    return;
  }

  const int q0w = q0 + wid * 32;
  // Q fragments (B-operand): lane holds Q[s=l31][ds*16 + hi*8 .. +7]
  const u16* qp = qb + ((size_t)bh * 2048 + q0w + l31) * 64;
  short8 qf0 = *(const short8*)(qp + hi * 8);
  short8 qf1 = *(const short8*)(qp + 16 + hi * 8);
  short8 qf2 = *(const short8*)(qp + 32 + hi * 8);
  short8 qf3 = *(const short8*)(qp + 48 + hi * 8);

  f32x16 oa0 = {0.f,0.f,0.f,0.f,0.f,0.f,0.f,0.f,0.f,0.f,0.f,0.f,0.f,0.f,0.f,0.f};
  f32x16 oa1 = oa0;
  float m_run = -1e30f, l_run = 0.f;

  const int swz = (l31 & 7) << 3;  // u16-unit XOR for LDS reads
  const int nt = (len + 63) >> 6;
  for (int kt = 0; kt < nt; ++kt) {
    const int t0 = kt * 64;
    __syncthreads();
    // stage K[64][64] and V^T[64][64]; pre-swizzled global source, linear LDS dest
#pragma unroll
    for (int c = 0; c < 2; ++c) {
      const int ck = c * 256 + wid * 64 + l;       // chunk 0..511
      const int r = ck >> 3;
      const int j = (ck & 7) ^ (r & 7);
      gload_lds16(kb + ((size_t)bh * 2048 + t0 + r) * 64 + j * 8,
                  &sm[(c * 256 + wid * 64) * 8]);
      gload_lds16(vT + ((size_t)bh * 64 + r) * 2048 + t0 + j * 8,
                  &sm[4096 + (c * 256 + wid * 64) * 8]);
    }
    __syncthreads();

    // QK^T swapped: sc[t][s], lane holds col s=l31, regs -> t
    f32x16 sc0 = {0.f,0.f,0.f,0.f,0.f,0.f,0.f,0.f,0.f,0.f,0.f,0.f,0.f,0.f,0.f,0.f};
    f32x16 sc1 = sc0;
#pragma unroll
    for (int ds = 0; ds < 4; ++ds) {
      const int col = (ds * 16 + hi * 8) ^ swz;
      const short8 kf0 = *(const short8*)&sm[(0 + l31) * 64 + col];
      const short8 kf1 = *(const short8*)&sm[(32 + l31) * 64 + col];
      const short8 qf = (ds == 0) ? qf0 : (ds == 1) ? qf1 : (ds == 2) ? qf2 : qf3;
      sc0 = __builtin_amdgcn_mfma_f32_32x32x16_bf16(kf0, qf, sc0, 0, 0, 0);
      sc1 = __builtin_amdgcn_mfma_f32_32x32x16_bf16(kf1, qf, sc1, 0, 0, 0);
    }

    if (t0 + 64 > len) {  // key-pad mask on last partial tile
      const int tb = t0 + 4 * hi;
#pragma unroll
      for (int i = 0; i < 16; ++i) {
        const int tg = tb + (i & 3) + 8 * (i >> 2);
        if (tg >= len) sc0[i] = -1e30f;
        if (tg + 32 >= len) sc1[i] = -1e30f;
      }
    }

    // online softmax fully in-register (lane owns query s=l31; partner lane^32
    // holds the other 32 t-values of the same row)
    float mt = sc0[0];
#pragma unroll
    for (int i = 1; i < 16; ++i) mt = fmaxf(mt, sc0[i]);
#pragma unroll
    for (int i = 0; i < 16; ++i) mt = fmaxf(mt, sc1[i]);
    mt = fmaxf(mt, __shfl_xor(mt, 32, 64));
    const float mnew = fmaxf(m_run, mt);
    const float fac = __expf(m_run - mnew);
    m_run = mnew;
    float sum = 0.f;
#pragma unroll
    for (int i = 0; i < 16; ++i) { sc0[i] = __expf(sc0[i] - mnew); sum += sc0[i]; }
#pragma unroll
    for (int i = 0; i < 16; ++i) { sc1[i] = __expf(sc1[i] - mnew); sum += sc1[i]; }
    sum += __shfl_xor(sum, 32, 64);
    l_run = l_run * fac + sum;
#pragma unroll
    for (int i = 0; i < 16; ++i) { oa0[i] *= fac; oa1[i] *= fac; }

    // pack P to bf16 pairs: word k covers t = {0,2,8,10,16,18,24,26}[k]+(0,1) +4hi
    unsigned w[16];
#pragma unroll
    for (int k = 0; k < 8; ++k) w[k] = cvtpk(sc0[2 * k], sc0[2 * k + 1]);
#pragma unroll
    for (int k = 0; k < 8; ++k) w[8 + k] = cvtpk(sc1[2 * k], sc1[2 * k + 1]);
    // build B-operand fragments pw[4g..4g+3] for k-slices g=0..3 (t 16g..16g+15)
    unsigned pw[16];
#pragma unroll
    for (int s = 0; s < 2; ++s) {
#pragma unroll
      for (int half = 0; half < 2; ++half) {
        const unsigned a0 = w[8 * s + 4 * half + 0], a1 = w[8 * s + 4 * half + 1];
        const unsigned a2 = w[8 * s + 4 * half + 2], a3 = w[8 * s + 4 * half + 3];
        const unsigned e0 = (unsigned)__shfl_xor((int)(hi ? a0 : a2), 32, 64);
        const unsigned e1 = (unsigned)__shfl_xor((int)(hi ? a1 : a3), 32, 64);
        const int o = s * 8 + half * 4;
        pw[o + 0] = hi ? e0 : a0;
        pw[o + 1] = hi ? e1 : a1;
        pw[o + 2] = hi ? a2 : e0;
        pw[o + 3] = hi ? a3 : e1;
      }
    }
    // PV: O^T[d][s] += V^T[d][t] . P[s][t] ; A = V^T rows (LDS), B = P frags
#pragma unroll
    for (int g = 0; g < 4; ++g) {
      union { unsigned u[4]; short8 s8; } pk;
      pk.u[0] = pw[4 * g + 0]; pk.u[1] = pw[4 * g + 1];
      pk.u[2] = pw[4 * g + 2]; pk.u[3] = pw[4 * g + 3];
      const int col = (g * 16 + hi * 8) ^ swz;
      const short8 vf0 = *(const short8*)&sm[4096 + (0 + l31) * 64 + col];
      const short8 vf1 = *(const short8*)&sm[4096 + (32 + l31) * 64 + col];
      oa0 = __builtin_amdgcn_mfma_f32_32x32x16_bf16(vf0, pk.s8, oa0, 0, 0, 0);
      oa1 = __builtin_amdgcn_mfma_f32_32x32x16_bf16(vf1, pk.s8, oa1, 0, 0, 0);
    }
  }

  __syncthreads();  // all warps done with K/V LDS before epilogue reuse
  const float invl = 1.0f / l_run;
  u16* ow = &sm[wid * 2304];  // per-warp [32 s][72 d-stride] (64 data + 8 pad)
#pragma unroll
  for (int i = 0; i < 16; ++i) {
    const int d0 = (i & 3) + 8 * (i >> 2) + 4 * hi;
    ow[l31 * 72 + d0] = f2bf(oa0[i] * invl);
    ow[l31 * 72 + 32 + d0] = f2bf(oa1[i] * invl);
  }
  short8 z = {0, 0, 0, 0, 0, 0, 0, 0};
#pragma unroll
  for (int c = 0; c < 4; ++c) {
    const int ck = c * 64 + l;  // 256 chunks = 32 rows x 8
    const int r = ck >> 3, j = ck & 7;
    short8 v = *(const short8*)&ow[r * 72 + j * 8];
    if (q0w + r >= len) v = z;  // zero padded query rows
    *(short8*)&obuf[((size_t)b * 2048 + q0w + r) * 1024 + h * 64 + j * 8] = v;
  }
}

// ---------------- launch ------------------------------------------------------
extern "C" void kernel_launch(void* const* d_in, const int* in_sizes, int n_in,
                              void* d_out, int out_size, void* d_ws, size_t ws_size,
                              hipStream_t stream) {
  const float* src = (const float*)d_in[0];
  const unsigned char* mask = (const unsigned char*)d_in[1];
  const float* Wq = (const float*)d_in[2];
  const float* Wk = (const float*)d_in[3];
  const float* Wv = (const float*)d_in[4];
  const float* Wo = (const float*)d_in[5];
  const float* g1 = (const float*)d_in[6];
  const float* g2 = (const float*)d_in[7];
  const float* W1 = (const float*)d_in[8];
  const float* V1 = (const float*)d_in[9];
  const float* W2 = (const float*)d_in[10];
  float* out = (float*)d_out;
  char* ws = (char*)d_ws;

  int* lens   = (int*)ws;
  u16* WqkvT  = (u16*)(ws + 256);        // [3072][1024]
  u16* WoT    = (u16*)(ws + 6291712);    // [1024][1024]
  u16* W1T    = (u16*)(ws + 8388864);    // [4096][1024]
  u16* V1T    = (u16*)(ws + 16777472);   // [4096][1024]
  u16* W2T    = (u16*)(ws + 25166080);   // [1024][4096]
  u16* xb     = (u16*)(ws + 33554688);   // [8192][1024] bf16 (x, later y)
  u16* qbf    = (u16*)(ws + 50331904);   // [64][2048][64] (pre-scaled by 1/8)
  u16* kbf    = (u16*)(ws + 67109120);   // [64][2048][64]
  u16* vTb    = (u16*)(ws + 83886336);   // [64][64][2048]
  u16* obf    = (u16*)(ws + 100663552);  // [8192][1024]
  u16* c1     = qbf;                     // [8192][4096] reuses q|k|vT|o region

  compute_lens<<<1, 256, 0, stream>>>(mask, lens);
  convT<<<dim3(2, 32, 16), 256, 0, stream>>>(Wq, WqkvT, 1024, 64, 65536, 65536);
  convT<<<dim3(2, 32, 16), 256, 0, stream>>>(Wk, WqkvT + 1024 * 1024, 1024, 64, 65536, 65536);
  convT<<<dim3(2, 32, 16), 256, 0, stream>>>(Wv, WqkvT + 2048 * 1024, 1024, 64, 65536, 65536);
  convT<<<dim3(32, 32, 1), 256, 0, stream>>>(Wo, WoT, 1024, 1024, 0, 0);
  convT<<<dim3(128, 32, 1), 256, 0, stream>>>(W1, W1T, 1024, 4096, 0, 0);
  convT<<<dim3(128, 32, 1), 256, 0, stream>>>(V1, V1T, 1024, 4096, 0, 0);
  convT<<<dim3(32, 128, 1), 256, 0, stream>>>(W2, W2T, 4096, 1024, 0, 0);

  rmsnorm_kernel<<<8192, 256, 0, stream>>>(src, g1, xb);
  gemm_bf16<MQKV><<<dim3(24, 64), 256, 0, stream>>>(xb, WqkvT, 1024, 3072,
                                                    qbf, kbf, vTb, nullptr, nullptr, nullptr);
  attn2_kernel<<<dim3(64, 16), 256, 0, stream>>>(qbf, kbf, vTb, obf, lens);
  gemm_bf16<MSA><<<dim3(8, 64), 256, 0, stream>>>(obf, WoT, 1024, 1024,
                                                  nullptr, nullptr, nullptr, out, src, nullptr);
  rmsnorm_kernel<<<8192, 256, 0, stream>>>(out, g2, xb);
  gemm_bf16<MB16><<<dim3(32, 64), 256, 0, stream>>>(xb, W1T, 1024, 4096,
                                                    nullptr, nullptr, nullptr, nullptr, nullptr, c1);
  gemm_bf16<MSILU><<<dim3(32, 64), 256, 0, stream>>>(xb, V1T, 1024, 4096,
                                                     nullptr, nullptr, nullptr, nullptr, nullptr, c1);
  gemm_bf16<MFF2><<<dim3(8, 64), 256, 0, stream>>>(c1, W2T, 4096, 1024,
                                                   nullptr, nullptr, nullptr, out, nullptr, nullptr);
}